// Round 16
// baseline (2167.529 us; speedup 1.0000x reference)
//
#include <hip/hip_runtime.h>

#define B_ 2
#define N_ 8192
#define D_ 128
#define KNN_ 16
#define R_ (B_*N_*KNN_)          // 262144 rows
#define BNEPS 1e-5f
#define AMB_CAP 512
#define TIE_PATTERN 0x1u
#define SVCAP 512                // per-wave survivor cap (=> <=8 per lane, lossless)

typedef short bf16x8 __attribute__((ext_vector_type(8)));
typedef float f32x4  __attribute__((ext_vector_type(4)));

__device__ __forceinline__ float gelu_f(float x) {
  return 0.5f * x * (1.0f + erff(x * 0.70710678118654752f));
}
__device__ __forceinline__ short f2bf(float x) {   // RNE f32->bf16
  unsigned u = __float_as_uint(x);
  u += 0x7fffu + ((u >> 16) & 1u);
  return (short)(u >> 16);
}
__device__ __forceinline__ float wave_sum64(float v) {
#pragma unroll
  for (int off = 32; off > 0; off >>= 1) v += __shfl_xor(v, off);
  return v;
}

// predicated sorted-insert, top-L ascending by (d2, j) lex
template<int L>
__device__ __forceinline__ void insL(float (&md)[L], int (&mi)[L], float d2, int j) {
  bool l[L];
#pragma unroll
  for (int u = 0; u < L; ++u)
    l[u] = (md[u] < d2) || (md[u] == d2 && mi[u] < j);
#pragma unroll
  for (int u = L-1; u >= 1; --u) {
    md[u] = l[u] ? md[u] : (l[u-1] ? d2 : md[u-1]);
    mi[u] = l[u] ? mi[u] : (l[u-1] ? j  : mi[u-1]);
  }
  md[0] = l[0] ? md[0] : d2;
  mi[0] = l[0] ? mi[0] : j;
}

// wave-wide: 17 sequential lex-argmin extractions over per-lane sorted lists.
template<int L>
__device__ __forceinline__ void wave_select17(float (&md)[L], int (&mi)[L],
                                              int lane, int qid, int* outp,
                                              int* amb, int* ambcnt) {
  float v15 = 0.0f, v16 = 0.0f; int j16 = -1;
  for (int r = 0; r < 17; ++r) {
    float cd = md[0]; int ci = mi[0];
#pragma unroll
    for (int off = 32; off > 0; off >>= 1) {
      const float od = __shfl_xor(cd, off);
      const int   oi = __shfl_xor(ci, off);
      if (od < cd || (od == cd && oi < ci)) { cd = od; ci = oi; }
    }
    const bool won = (md[0] == cd) && (mi[0] == ci);
#pragma unroll
    for (int u = 0; u < L-1; ++u) {
      md[u] = won ? md[u+1] : md[u];
      mi[u] = won ? mi[u+1] : mi[u];
    }
    md[L-1] = won ? INFINITY : md[L-1];
    mi[L-1] = won ? 0x7fffffff : mi[L-1];
    if (lane == 0) {
      if (r < 16) outp[r] = ci;
      if (r == 15) v15 = cd;
      if (r == 16) { v16 = cd; j16 = ci; }
    }
  }
  if (lane == 0 && v15 == v16) {
    int slot = atomicAdd(ambcnt, 1);
    if (slot < AMB_CAP) { amb[2*slot] = qid; amb[2*slot+1] = j16; }
  }
}

// d2 for LDS SoA points (J0, J0+1); bit-matches the NumPy ref formula:
//   sq = ((x*x + y*y) + z*z), dot = ((x*qx + y*qy) + z*qz), d2=(sqi+sq)-2*dot
#define D2LDS(J0, DA, DB)                                                 \
  {                                                                       \
    const float2 xv = *(const float2*)(xs + (J0));                        \
    const float2 yv = *(const float2*)(ys + (J0));                        \
    const float2 zv = *(const float2*)(zs + (J0));                        \
    { const float sq_ = (xv.x*xv.x + yv.x*yv.x) + zv.x*zv.x;              \
      const float dt_ = (xv.x*qx + yv.x*qy) + zv.x*qz;                    \
      DA = (sqi + sq_) - 2.0f*dt_; }                                      \
    { const float sq_ = (xv.y*xv.y + yv.y*yv.y) + zv.y*zv.y;              \
      const float dt_ = (xv.y*qx + yv.y*qy) + zv.y*qz;                    \
      DB = (sqi + sq_) - 2.0f*dt_; }                                      \
  }

// ---------------------------------------------------------------- kNN
// Points LDS-resident (96 KB SoA); 16 queries/block (4 waves x 4 sequential).
// Same formula/comparator/threshold/compaction as r15 => bit-identical result.
__global__ __launch_bounds__(256) void k_knn(const float* __restrict__ pts,
                                             int* __restrict__ knn,
                                             int* __restrict__ amb,
                                             int* __restrict__ ambcnt) {
#pragma clang fp contract(off)
  const int lane = threadIdx.x & 63;
  const int w    = threadIdx.x >> 6;
  const int b    = blockIdx.x >> 9;             // 512 blocks per batch
  const float* P = pts + (size_t)b * N_ * 3;

  __shared__ __align__(16) float xs[N_];        // 32 KB
  __shared__ __align__(16) float ys[N_];        // 32 KB
  __shared__ __align__(16) float zs[N_];        // 32 KB
  __shared__ float sv[4 * 2 * SVCAP];           // 16 KB
  float* svw = sv + w * 2 * SVCAP;

  for (int p = threadIdx.x; p < N_; p += 256) {
    xs[p] = P[p*3+0];
    ys[p] = P[p*3+1];
    zs[p] = P[p*3+2];
  }
  __syncthreads();

  for (int sub = 0; sub < 4; ++sub) {
    const int qid = blockIdx.x * 16 + w * 4 + sub;
    const int i   = qid & (N_ - 1);
    const float qx = xs[i], qy = ys[i], qz = zs[i];
    const float sqi = (qx*qx + qy*qy) + qz*qz;

    // ---------------- pass A: threshold from 512 samples
    float mv = INFINITY;
#pragma unroll
    for (int s = 0; s < 4; ++s) {
      const int j0 = 2*lane + 128*s;
      float da, db;
      D2LDS(j0, da, db)
      mv = fminf(mv, fminf(da, db));
    }
    float thr = 0.0f;
    {
      float v = mv;
      for (int r = 0; r < 17; ++r) {
        float m = v;
#pragma unroll
        for (int off = 32; off > 0; off >>= 1) m = fminf(m, __shfl_xor(m, off));
        if (r == 16) thr = m;
        v = (v == m) ? INFINITY : v;
      }
    }

    // ---------------- pass B: filter + scalar-ballot compaction
    int base = 0;
#pragma unroll 4
    for (int k = 0; k < 64; ++k) {
      const int j0 = (k*64 + lane) * 2;
      float da, db;
      D2LDS(j0, da, db)
      const bool pa = (da <= thr);
      const bool pb = (db <= thr);
      const unsigned long long lt = (1ull << lane) - 1ull;
      const unsigned long long ma = __ballot(pa);
      const int idxa = base + (int)__popcll(ma & lt);
      const int basea = base + (int)__popcll(ma);
      const unsigned long long mb = __ballot(pb);
      const int idxb = basea + (int)__popcll(mb & lt);
      base = basea + (int)__popcll(mb);
      if (pa && idxa < SVCAP) { svw[2*idxa] = da; svw[2*idxa+1] = __int_as_float(j0); }
      if (pb && idxb < SVCAP) { svw[2*idxb] = db; svw[2*idxb+1] = __int_as_float(j0+1); }
    }
    const int SC = base;
    int* outp = knn + (size_t)qid * KNN_;

    if (SC <= SVCAP) {
      float md[8]; int mi[8];
#pragma unroll
      for (int u = 0; u < 8; ++u) { md[u] = INFINITY; mi[u] = 0x7fffffff; }
      for (int u = lane; u < SC; u += 64)
        insL<8>(md, mi, svw[2*u], __float_as_int(svw[2*u+1]));
      wave_select17<8>(md, mi, lane, qid, outp, amb, ambcnt);
    } else {
      // exact fallback (astronomically rare): full rescan, list-17 per lane
      float md[17]; int mi[17];
#pragma unroll
      for (int u = 0; u < 17; ++u) { md[u] = INFINITY; mi[u] = 0x7fffffff; }
      for (int k = 0; k < 64; ++k) {
        const int j0 = (k*64 + lane) * 2;
        float da, db;
        D2LDS(j0, da, db)
        insL<17>(md, mi, da, j0);
        insL<17>(md, mi, db, j0+1);
      }
      wave_select17<17>(md, mi, lane, qid, outp, amb, ambcnt);
    }
  }
}

// ---------------------------------------------------------------- tie resolver
__global__ void k_resolve(const int* __restrict__ ambcnt,
                          int* __restrict__ amb,
                          int* __restrict__ knn) {
  if (threadIdx.x != 0 || blockIdx.x != 0) return;
  int cnt = *ambcnt; if (cnt > AMB_CAP) cnt = AMB_CAP;
  for (int a = 1; a < cnt; ++a) {
    int q = amb[2*a], j = amb[2*a+1];
    int p = a - 1;
    while (p >= 0 && amb[2*p] > q) {
      amb[2*(p+1)] = amb[2*p]; amb[2*(p+1)+1] = amb[2*p+1]; --p;
    }
    amb[2*(p+1)] = q; amb[2*(p+1)+1] = j;
  }
  for (int p = 0; p < cnt && p < 32; ++p) {
    if ((TIE_PATTERN >> p) & 1u) {
      const int qid = amb[2*p];
      knn[(size_t)qid * KNN_ + 15] = amb[2*p+1];
    }
  }
}

// ---------------------------------------------------------------- pos MLP stage 1 (h1) + 3-ch stats
__global__ __launch_bounds__(256) void k_h1(const float* __restrict__ pts,
                                            const int* __restrict__ knn,
                                            const float* __restrict__ Wd1,
                                            const float* __restrict__ bd1,
                                            float* __restrict__ h1,
                                            float* __restrict__ pstat3) {
  float w[9], bb[3];
#pragma unroll
  for (int u = 0; u < 9; ++u) w[u] = Wd1[u];
#pragma unroll
  for (int u = 0; u < 3; ++u) bb[u] = bd1[u];

  float s0=0,s1=0,s2=0,q0=0,q1=0,q2=0;
  const int tid = blockIdx.x * blockDim.x + threadIdx.x;
  const int stride = gridDim.x * blockDim.x;
  for (int row = tid; row < R_; row += stride) {
    const int b  = row >> 17;
    const int n  = (row >> 4) & (N_-1);
    const int gi = knn[row];
    const float* P = pts + (size_t)b * N_ * 3;
    const float px = P[n*3+0] - P[gi*3+0];
    const float py = P[n*3+1] - P[gi*3+1];
    const float pz = P[n*3+2] - P[gi*3+2];
    const float h0 = px*w[0] + py*w[3] + pz*w[6] + bb[0];
    const float h1v= px*w[1] + py*w[4] + pz*w[7] + bb[1];
    const float h2 = px*w[2] + py*w[5] + pz*w[8] + bb[2];
    h1[(size_t)row*3+0] = h0; h1[(size_t)row*3+1] = h1v; h1[(size_t)row*3+2] = h2;
    s0 += h0; s1 += h1v; s2 += h2;
    q0 += h0*h0; q1 += h1v*h1v; q2 += h2*h2;
  }
  s0 = wave_sum64(s0); s1 = wave_sum64(s1); s2 = wave_sum64(s2);
  q0 = wave_sum64(q0); q1 = wave_sum64(q1); q2 = wave_sum64(q2);
  __shared__ float red[4][6];
  const int lane = threadIdx.x & 63, wv = threadIdx.x >> 6;
  if (lane == 0) { red[wv][0]=s0; red[wv][1]=s1; red[wv][2]=s2; red[wv][3]=q0; red[wv][4]=q1; red[wv][5]=q2; }
  __syncthreads();
  if (threadIdx.x == 0) {
    float a[6] = {0,0,0,0,0,0};
#pragma unroll
    for (int w2 = 0; w2 < 4; ++w2)
#pragma unroll
      for (int u = 0; u < 6; ++u) a[u] += red[w2][u];
#pragma unroll
    for (int u = 0; u < 6; ++u) pstat3[blockIdx.x*6 + u] = a[u];
  }
}

__global__ void k_fin3(const float* __restrict__ pstat3, int nb,
                       const float* __restrict__ gd, const float* __restrict__ betad,
                       float* __restrict__ coefd) {
  const int c = threadIdx.x;
  if (c < 3) {
    float S = 0, Q = 0;
    for (int p = 0; p < nb; ++p) { S += pstat3[p*6+c]; Q += pstat3[p*6+3+c]; }
    const float m = S / (float)R_;
    const float v = Q / (float)R_ - m*m;
    const float a = gd[c] * rsqrtf(v + BNEPS);
    coefd[c] = a; coefd[3+c] = betad[c] - m*a;
  }
}

// ---------------------------------------------------------------- f32 GEMM pieces (k_gemm_q / k_final)
#define STAGE_B(W, BS, KC, T)                                              \
  _Pragma("unroll")                                                        \
  for (int qd = 0; qd < 4; ++qd) {                                         \
    int slot = (T)*4 + qd;                                                 \
    int kk = slot >> 5, c4 = slot & 31;                                    \
    *(float4*)((BS) + kk*128 + c4*4) =                                     \
        *(const float4*)((W) + (size_t)((KC)*32 + kk)*128 + c4*4);         \
  }

#define GEMM_INNER(AS, BS, ACC, TX, TY)                                    \
  _Pragma("unroll")                                                        \
  for (int kg = 0; kg < 8; ++kg) {                                         \
    float4 b0 = *(const float4*)((BS) + (kg*4+0)*128 + (TX)*4);            \
    float4 b1 = *(const float4*)((BS) + (kg*4+1)*128 + (TX)*4);            \
    float4 b2 = *(const float4*)((BS) + (kg*4+2)*128 + (TX)*4);            \
    float4 b3 = *(const float4*)((BS) + (kg*4+3)*128 + (TX)*4);            \
    _Pragma("unroll")                                                      \
    for (int r = 0; r < 8; ++r) {                                          \
      float4 a = *(const float4*)((AS) + ((TY)*8+r)*32 + kg*4);            \
      ACC[r][0] += a.x*b0.x + a.y*b1.x + a.z*b2.x + a.w*b3.x;              \
      ACC[r][1] += a.x*b0.y + a.y*b1.y + a.z*b2.y + a.w*b3.y;              \
      ACC[r][2] += a.x*b0.z + a.y*b1.z + a.z*b2.z + a.w*b3.z;              \
      ACC[r][3] += a.x*b0.w + a.y*b1.w + a.z*b2.w + a.w*b3.w;              \
    }                                                                      \
  }

// Stage W (f32, row-major [K][128]) K-chunk kc as TRANSPOSED bf16 Bst[col][k],
// row stride 40 shorts (80B) for bank safety.
#define STAGE_BT(W, BST, KC, T)                                            \
  {                                                                        \
    const int kk_ = (T) >> 5;                                              \
    const int c4_ = ((T) & 31) * 4;                                        \
    _Pragma("unroll")                                                      \
    for (int p_ = 0; p_ < 4; ++p_) {                                       \
      const int k_ = (KC)*32 + p_*8 + kk_;                                 \
      float4 wv_ = *(const float4*)((W) + (size_t)k_*128 + c4_);           \
      (BST)[(c4_+0)*40 + (p_*8+kk_)] = f2bf(wv_.x);                        \
      (BST)[(c4_+1)*40 + (p_*8+kk_)] = f2bf(wv_.y);                        \
      (BST)[(c4_+2)*40 + (p_*8+kk_)] = f2bf(wv_.z);                        \
      (BST)[(c4_+3)*40 + (p_*8+kk_)] = f2bf(wv_.w);                        \
    }                                                                      \
  }

// ---------------------------------------------------------------- q = feats@Wq + bq (f32)
__global__ __launch_bounds__(256) void k_gemm_q(const float* __restrict__ X,
                                                const float* __restrict__ W,
                                                const float* __restrict__ bias,
                                                float* __restrict__ Y) {
  __shared__ float As[64*32];
  __shared__ float Bs[32*128];
  const int t = threadIdx.x, tx = t & 31, ty = t >> 5;
  const size_t row0 = (size_t)blockIdx.x * 64;
  float acc[8][4] = {};
  for (int kc = 0; kc < 4; ++kc) {
#pragma unroll
    for (int qd = 0; qd < 2; ++qd) {
      int slot = t*2 + qd;
      int r = slot >> 3, c4 = slot & 7;
      *(float4*)(As + r*32 + c4*4) =
          *(const float4*)(X + (row0 + r)*128 + kc*32 + c4*4);
    }
    STAGE_B(W, Bs, kc, t)
    __syncthreads();
    GEMM_INNER(As, Bs, acc, tx, ty)
    __syncthreads();
  }
  const float4 bia = *(const float4*)(bias + tx*4);
#pragma unroll
  for (int r = 0; r < 8; ++r) {
    float4 o;
    o.x = acc[r][0] + bia.x; o.y = acc[r][1] + bia.y;
    o.z = acc[r][2] + bia.z; o.w = acc[r][3] + bia.w;
    *(float4*)(Y + (row0 + ty*8 + r)*128 + tx*4) = o;
  }
}

// ---------------------------------------------------------------- gamma0 via bf16 MFMA
__global__ __launch_bounds__(256) void k_gamma0(const float* __restrict__ feats,
                                                const int* __restrict__ knn,
                                                const float* __restrict__ Wk,
                                                const float* __restrict__ bk,
                                                const float* __restrict__ qbuf,
                                                const float* __restrict__ h1,
                                                const float* __restrict__ coefd,
                                                const float* __restrict__ Wd2,
                                                const float* __restrict__ bd2,
                                                float* __restrict__ g) {
  __shared__ short As[64*40];     // bf16 A tile [64 rows][32 k] pad->40
  __shared__ short Bst[128*40];   // bf16 B^T [128 cols][32 k] pad->40
  __shared__ int gidx[64];
  const int t = threadIdx.x;
  const int l = t & 63, w = t >> 6;
  const size_t row0 = (size_t)blockIdx.x * 64;
  if (t < 64) {
    const int grow = (int)row0 + t;
    gidx[t] = (grow >> 17) * N_ + knn[grow];
  }
  __syncthreads();

  f32x4 acc[8] = {};
  for (int kc = 0; kc < 4; ++kc) {
    {
      const int r = t >> 2, c8 = (t & 3) * 8;
      const float* src = feats + (size_t)gidx[r]*128 + kc*32 + c8;
      float4 v0 = *(const float4*)(src);
      float4 v1 = *(const float4*)(src + 4);
      short* dst = As + r*40 + c8;
      dst[0]=f2bf(v0.x); dst[1]=f2bf(v0.y); dst[2]=f2bf(v0.z); dst[3]=f2bf(v0.w);
      dst[4]=f2bf(v1.x); dst[5]=f2bf(v1.y); dst[6]=f2bf(v1.z); dst[7]=f2bf(v1.w);
    }
    STAGE_BT(Wk, Bst, kc, t)
    __syncthreads();
    bf16x8 af = *(bf16x8*)(As + (w*16 + (l & 15))*40 + 8*(l >> 4));
#pragma unroll
    for (int ct = 0; ct < 8; ++ct) {
      bf16x8 bf = *(bf16x8*)(Bst + (ct*16 + (l & 15))*40 + 8*(l >> 4));
      acc[ct] = __builtin_amdgcn_mfma_f32_16x16x32_bf16(af, bf, acc[ct], 0, 0, 0);
    }
    __syncthreads();
  }

  const float ad0 = coefd[0], ad1 = coefd[1], ad2 = coefd[2];
  const float cd0 = coefd[3], cd1 = coefd[4], cd2 = coefd[5];
  const int r4 = (l >> 4) * 4;
  float e0[4], e1[4], e2[4];
  size_t grows[4];
#pragma unroll
  for (int r = 0; r < 4; ++r) {
    grows[r] = row0 + w*16 + r4 + r;
    e0[r] = gelu_f(ad0 * h1[grows[r]*3+0] + cd0);
    e1[r] = gelu_f(ad1 * h1[grows[r]*3+1] + cd1);
    e2[r] = gelu_f(ad2 * h1[grows[r]*3+2] + cd2);
  }
#pragma unroll
  for (int ct = 0; ct < 8; ++ct) {
    const int col = ct*16 + (l & 15);
    const float bkc  = bk[col];
    const float w20c = Wd2[col], w21c = Wd2[128+col], w22c = Wd2[256+col];
    const float b24c = bd2[col];
#pragma unroll
    for (int r = 0; r < 4; ++r) {
      const float qv = qbuf[(grows[r] >> 4)*128 + col];
      g[grows[r]*128 + col] =
          qv - (acc[ct][r] + bkc) + (e0[r]*w20c + e1[r]*w21c + e2[r]*w22c + b24c);
    }
  }
}

// ---------------------------------------------------------------- 128-ch BN stats over [R_][128]
__global__ __launch_bounds__(256) void k_stat128(const float* __restrict__ X,
                                                 float* __restrict__ pstat) {
  const int t = threadIdx.x;
  const int c = t & 127, h = t >> 7;
  const int rows = R_ / 512;
  const size_t base = (size_t)blockIdx.x * rows * 128;
  float s = 0, q = 0;
  for (int r = h; r < rows; r += 2) {
    const float x = X[base + (size_t)r*128 + c];
    s += x; q += x*x;
  }
  __shared__ float ls[256], lq[256];
  ls[t] = s; lq[t] = q;
  __syncthreads();
  if (t < 128) {
    pstat[blockIdx.x*256 + t]       = ls[t] + ls[t+128];
    pstat[blockIdx.x*256 + 128 + t] = lq[t] + lq[t+128];
  }
}

__global__ __launch_bounds__(128) void k_fin128(const float* __restrict__ pstat, int nb,
                                                const float* __restrict__ gamma,
                                                const float* __restrict__ beta,
                                                float* __restrict__ coef) {
  const int c = threadIdx.x;
  float S = 0, Q = 0;
  for (int p = 0; p < nb; ++p) { S += pstat[p*256 + c]; Q += pstat[p*256 + 128 + c]; }
  const float m = S / (float)R_;
  const float v = Q / (float)R_ - m*m;
  const float a = gamma[c] * rsqrtf(v + BNEPS);
  coef[c] = a; coef[128 + c] = beta[c] - m*a;
}

// ---------------------------------------------------------------- X <- gelu(bn(X)) @ W + bias via bf16 MFMA (in place)
__global__ __launch_bounds__(256) void k_bngemm(float* __restrict__ g,
                                                const float* __restrict__ coef,
                                                const float* __restrict__ W,
                                                const float* __restrict__ bias) {
  __shared__ short As[64*40];
  __shared__ short Bst[128*40];
  const int t = threadIdx.x;
  const int l = t & 63, w = t >> 6;
  const size_t row0 = (size_t)blockIdx.x * 64;

  f32x4 acc[8] = {};
  for (int kc = 0; kc < 4; ++kc) {
    {
      const int r = t >> 2, c8 = (t & 3) * 8;
      const int cb = kc*32 + c8;
      const float* src = g + (row0 + r)*128 + cb;
      float4 v0 = *(const float4*)(src);
      float4 v1 = *(const float4*)(src + 4);
      const float4 a0 = *(const float4*)(coef + cb);
      const float4 a1 = *(const float4*)(coef + cb + 4);
      const float4 b0 = *(const float4*)(coef + 128 + cb);
      const float4 b1 = *(const float4*)(coef + 128 + cb + 4);
      short* dst = As + r*40 + c8;
      dst[0]=f2bf(gelu_f(a0.x*v0.x+b0.x)); dst[1]=f2bf(gelu_f(a0.y*v0.y+b0.y));
      dst[2]=f2bf(gelu_f(a0.z*v0.z+b0.z)); dst[3]=f2bf(gelu_f(a0.w*v0.w+b0.w));
      dst[4]=f2bf(gelu_f(a1.x*v1.x+b1.x)); dst[5]=f2bf(gelu_f(a1.y*v1.y+b1.y));
      dst[6]=f2bf(gelu_f(a1.z*v1.z+b1.z)); dst[7]=f2bf(gelu_f(a1.w*v1.w+b1.w));
    }
    STAGE_BT(W, Bst, kc, t)
    __syncthreads();
    bf16x8 af = *(bf16x8*)(As + (w*16 + (l & 15))*40 + 8*(l >> 4));
#pragma unroll
    for (int ct = 0; ct < 8; ++ct) {
      bf16x8 bf = *(bf16x8*)(Bst + (ct*16 + (l & 15))*40 + 8*(l >> 4));
      acc[ct] = __builtin_amdgcn_mfma_f32_16x16x32_bf16(af, bf, acc[ct], 0, 0, 0);
    }
    __syncthreads();
  }

  const int r4 = (l >> 4) * 4;
#pragma unroll
  for (int ct = 0; ct < 8; ++ct) {
    const int col = ct*16 + (l & 15);
    const float bia = bias[col];
#pragma unroll
    for (int r = 0; r < 4; ++r) {
      g[(row0 + w*16 + r4 + r)*128 + col] = acc[ct][r] + bia;
    }
  }
}

// ---------------------------------------------------------------- final: softmax(gamma2) . (knnF@Wv+bv+pos) (f32)
__global__ __launch_bounds__(256) void k_final(const float* __restrict__ feats,
                                               const int* __restrict__ knn,
                                               const float* __restrict__ Wv,
                                               const float* __restrict__ bvb,
                                               const float* __restrict__ g,
                                               const float* __restrict__ h1,
                                               const float* __restrict__ coefd,
                                               const float* __restrict__ Wd2,
                                               const float* __restrict__ bd2,
                                               float* __restrict__ out) {
  const int bn = blockIdx.x;
  const int t = threadIdx.x, tx = t & 31, ty = t >> 5;
  __shared__ float G[16*128];
  __shared__ float Af[16*128];
  __shared__ float Bs[32*128];
  __shared__ float red[8*128];
  __shared__ int gidx[16];
  const size_t rowbase = (size_t)bn * 16;

  if (t < 16) gidx[t] = (bn >> 13) * N_ + knn[rowbase + t];
#pragma unroll
  for (int qd = 0; qd < 2; ++qd) {
    int slot = t*2 + qd;
    int r = slot >> 5, c4 = slot & 31;
    *(float4*)(G + r*128 + c4*4) = *(const float4*)(g + (rowbase + r)*128 + c4*4);
  }
  __syncthreads();

  if (t < 128) {
    float m = -INFINITY;
#pragma unroll
    for (int j = 0; j < 16; ++j) m = fmaxf(m, G[j*128 + t]);
    float e[16]; float s = 0;
#pragma unroll
    for (int j = 0; j < 16; ++j) { e[j] = expf(G[j*128 + t] - m); s += e[j]; }
    const float inv = 1.0f / s;
#pragma unroll
    for (int j = 0; j < 16; ++j) G[j*128 + t] = e[j] * inv;
  }
#pragma unroll
  for (int qd = 0; qd < 2; ++qd) {
    int slot = t*2 + qd;
    int r = slot >> 5, c4 = slot & 31;
    *(float4*)(Af + r*128 + c4*4) =
        *(const float4*)(feats + (size_t)gidx[r]*128 + c4*4);
  }
  __syncthreads();

  float acc[2][4] = {};
  for (int kc = 0; kc < 4; ++kc) {
    STAGE_B(Wv, Bs, kc, t)
    __syncthreads();
#pragma unroll
    for (int kg = 0; kg < 8; ++kg) {
      float4 b0 = *(const float4*)(Bs + (kg*4+0)*128 + tx*4);
      float4 b1 = *(const float4*)(Bs + (kg*4+1)*128 + tx*4);
      float4 b2 = *(const float4*)(Bs + (kg*4+2)*128 + tx*4);
      float4 b3 = *(const float4*)(Bs + (kg*4+3)*128 + tx*4);
#pragma unroll
      for (int rr = 0; rr < 2; ++rr) {
        const int j = ty + rr*8;
        float4 a = *(const float4*)(Af + j*128 + kc*32 + kg*4);
        acc[rr][0] += a.x*b0.x + a.y*b1.x + a.z*b2.x + a.w*b3.x;
        acc[rr][1] += a.x*b0.y + a.y*b1.y + a.z*b2.y + a.w*b3.y;
        acc[rr][2] += a.x*b0.z + a.y*b1.z + a.z*b2.z + a.w*b3.z;
        acc[rr][3] += a.x*b0.w + a.y*b1.w + a.z*b2.w + a.w*b3.w;
      }
    }
    __syncthreads();
  }

  const float4 bv4 = *(const float4*)(bvb + tx*4);
  const float ad0 = coefd[0], ad1 = coefd[1], ad2 = coefd[2];
  const float cd0 = coefd[3], cd1 = coefd[4], cd2 = coefd[5];
  const float4 w20 = *(const float4*)(Wd2 + 0*128 + tx*4);
  const float4 w21 = *(const float4*)(Wd2 + 1*128 + tx*4);
  const float4 w22 = *(const float4*)(Wd2 + 2*128 + tx*4);
  const float4 b24 = *(const float4*)(bd2 + tx*4);

  float4 part = {0, 0, 0, 0};
#pragma unroll
  for (int rr = 0; rr < 2; ++rr) {
    const int j = ty + rr*8;
    const size_t grow = rowbase + j;
    const float e0 = gelu_f(ad0 * h1[grow*3+0] + cd0);
    const float e1 = gelu_f(ad1 * h1[grow*3+1] + cd1);
    const float e2 = gelu_f(ad2 * h1[grow*3+2] + cd2);
    float4 val;
    val.x = acc[rr][0] + bv4.x + (e0*w20.x + e1*w21.x + e2*w22.x + b24.x);
    val.y = acc[rr][1] + bv4.y + (e0*w20.y + e1*w21.y + e2*w22.y + b24.y);
    val.z = acc[rr][2] + bv4.z + (e0*w20.z + e1*w21.z + e2*w22.z + b24.z);
    val.w = acc[rr][3] + bv4.w + (e0*w20.w + e1*w21.w + e2*w22.w + b24.w);
    const float4 rho = *(const float4*)(G + j*128 + tx*4);
    part.x += rho.x * val.x; part.y += rho.y * val.y;
    part.z += rho.z * val.z; part.w += rho.w * val.w;
  }
  *(float4*)(red + ty*128 + tx*4) = part;
  __syncthreads();
  if (t < 128) {
    float s = 0;
#pragma unroll
    for (int w = 0; w < 8; ++w) s += red[w*128 + t];
    out[(size_t)bn*128 + t] = s;
  }
}

// ---------------------------------------------------------------- launcher
extern "C" void kernel_launch(void* const* d_in, const int* in_sizes, int n_in,
                              void* d_out, int out_size, void* d_ws, size_t ws_size,
                              hipStream_t stream) {
  const float* feats  = (const float*)d_in[0];
  const float* pts    = (const float*)d_in[1];
  const float* Wq     = (const float*)d_in[2];
  const float* bq     = (const float*)d_in[3];
  const float* Wk     = (const float*)d_in[4];
  const float* bk     = (const float*)d_in[5];
  const float* Wv     = (const float*)d_in[6];
  const float* bv     = (const float*)d_in[7];
  const float* Wd1    = (const float*)d_in[8];
  const float* bd1    = (const float*)d_in[9];
  const float* Wd2    = (const float*)d_in[10];
  const float* bd2    = (const float*)d_in[11];
  const float* gd     = (const float*)d_in[12];
  const float* betad  = (const float*)d_in[13];
  const float* Wg1    = (const float*)d_in[14];
  const float* bg1    = (const float*)d_in[15];
  const float* Wg2    = (const float*)d_in[16];
  const float* bg2    = (const float*)d_in[17];
  const float* gg1    = (const float*)d_in[18];
  const float* betag1 = (const float*)d_in[19];
  const float* gg2    = (const float*)d_in[20];
  const float* betag2 = (const float*)d_in[21];
  float* out = (float*)d_out;

  char* ws = (char*)d_ws;
  int*   idx    = (int*)(ws + 0);                        // 1 MB
  float* h1     = (float*)(ws + (1u  << 20));            // 3 MB
  float* qbuf   = (float*)(ws + (4u  << 20));            // 8 MB
  float* pstat  = (float*)(ws + (12u << 20));            // 512 KB
  float* pstat3 = (float*)(ws + (13u << 20));            // 12 KB
  float* coefd  = (float*)(ws + (13u << 20) + (64u << 10));
  float* coef1  = coefd + 16;
  float* coef2  = coefd + 16 + 256;
  int*   amb    = (int*)(ws + (13u << 20) + (128u << 10)); // pairs
  int*   ambcnt = (int*)(ws + (13u << 20) + (192u << 10)); // 4 B
  float* g      = (float*)(ws + (16u << 20));            // 128 MB

  hipMemsetAsync(ambcnt, 0, 4, stream);
  k_knn    <<<(B_*N_)/16, 256, 0, stream>>>(pts, idx, amb, ambcnt);
  k_resolve<<<1, 64, 0, stream>>>(ambcnt, amb, idx);
  k_h1     <<<512, 256, 0, stream>>>(pts, idx, Wd1, bd1, h1, pstat3);
  k_fin3   <<<1, 64, 0, stream>>>(pstat3, 512, gd, betad, coefd);
  k_gemm_q <<<(B_*N_)/64, 256, 0, stream>>>(feats, Wq, bq, qbuf);
  k_gamma0 <<<R_/64, 256, 0, stream>>>(feats, idx, Wk, bk, qbuf, h1, coefd, Wd2, bd2, g);
  k_stat128<<<512, 256, 0, stream>>>(g, pstat);
  k_fin128 <<<1, 128, 0, stream>>>(pstat, 512, gg1, betag1, coef1);
  k_bngemm <<<R_/64, 256, 0, stream>>>(g, coef1, Wg1, bg1);
  k_stat128<<<512, 256, 0, stream>>>(g, pstat);
  k_fin128 <<<1, 128, 0, stream>>>(pstat, 512, gg2, betag2, coef2);
  k_bngemm <<<R_/64, 256, 0, stream>>>(g, coef2, Wg2, bg2);
  k_final  <<<B_*N_, 256, 0, stream>>>(feats, idx, Wv, bv, g, h1, coefd, Wd2, bd2, out);
}

// Round 17
// 1607.125 us; speedup vs baseline: 1.3487x; 1.3487x over previous
//
#include <hip/hip_runtime.h>

#define B_ 2
#define N_ 8192
#define D_ 128
#define KNN_ 16
#define R_ (B_*N_*KNN_)          // 262144 rows
#define BNEPS 1e-5f
#define AMB_CAP 512
#define TIE_PATTERN 0x1u
#define SVCAP 512                // per-query survivor cap (=> <=8 per lane, lossless)

typedef short bf16x8 __attribute__((ext_vector_type(8)));
typedef float f32x4  __attribute__((ext_vector_type(4)));

__device__ __forceinline__ float gelu_f(float x) {
  return 0.5f * x * (1.0f + erff(x * 0.70710678118654752f));
}
__device__ __forceinline__ short f2bf(float x) {   // RNE f32->bf16
  unsigned u = __float_as_uint(x);
  u += 0x7fffu + ((u >> 16) & 1u);
  return (short)(u >> 16);
}
__device__ __forceinline__ float wave_sum64(float v) {
#pragma unroll
  for (int off = 32; off > 0; off >>= 1) v += __shfl_xor(v, off);
  return v;
}

// predicated sorted-insert, top-L ascending by (d2, j) lex
template<int L>
__device__ __forceinline__ void insL(float (&md)[L], int (&mi)[L], float d2, int j) {
  bool l[L];
#pragma unroll
  for (int u = 0; u < L; ++u)
    l[u] = (md[u] < d2) || (md[u] == d2 && mi[u] < j);
#pragma unroll
  for (int u = L-1; u >= 1; --u) {
    md[u] = l[u] ? md[u] : (l[u-1] ? d2 : md[u-1]);
    mi[u] = l[u] ? mi[u] : (l[u-1] ? j  : mi[u-1]);
  }
  md[0] = l[0] ? md[0] : d2;
  mi[0] = l[0] ? mi[0] : j;
}

// wave-wide: 17 sequential lex-argmin extractions over per-lane sorted lists.
template<int L>
__device__ __forceinline__ void wave_select17(float (&md)[L], int (&mi)[L],
                                              int lane, int qid, int* outp,
                                              int* amb, int* ambcnt) {
  float v15 = 0.0f, v16 = 0.0f; int j16 = -1;
  for (int r = 0; r < 17; ++r) {
    float cd = md[0]; int ci = mi[0];
#pragma unroll
    for (int off = 32; off > 0; off >>= 1) {
      const float od = __shfl_xor(cd, off);
      const int   oi = __shfl_xor(ci, off);
      if (od < cd || (od == cd && oi < ci)) { cd = od; ci = oi; }
    }
    const bool won = (md[0] == cd) && (mi[0] == ci);
#pragma unroll
    for (int u = 0; u < L-1; ++u) {
      md[u] = won ? md[u+1] : md[u];
      mi[u] = won ? mi[u+1] : mi[u];
    }
    md[L-1] = won ? INFINITY : md[L-1];
    mi[L-1] = won ? 0x7fffffff : mi[L-1];
    if (lane == 0) {
      if (r < 16) outp[r] = ci;
      if (r == 15) v15 = cd;
      if (r == 16) { v16 = cd; j16 = ci; }
    }
  }
  if (lane == 0 && v15 == v16) {
    int slot = atomicAdd(ambcnt, 1);
    if (slot < AMB_CAP) { amb[2*slot] = qid; amb[2*slot+1] = j16; }
  }
}

// Load point pair (J0, J0+1) once; compute distances to BOTH queries.
// Formula bit-matches the NumPy ref: sq=((x*x+y*y)+z*z),
// dot=((x*qx+y*qy)+z*qz), d2=(sqi+sq)-2*dot.
#define D2PAIR(PP, J0, DA0, DB0, DA1, DB1)                                \
  {                                                                       \
    const float2 a_ = *(const float2*)((PP) + (size_t)(J0)*3);            \
    const float2 b_ = *(const float2*)((PP) + (size_t)(J0)*3 + 2);        \
    const float2 c_ = *(const float2*)((PP) + (size_t)(J0)*3 + 4);        \
    const float sqA_ = (a_.x*a_.x + a_.y*a_.y) + b_.x*b_.x;               \
    const float sqB_ = (b_.y*b_.y + c_.x*c_.x) + c_.y*c_.y;               \
    { const float dt_ = (a_.x*qx0 + a_.y*qy0) + b_.x*qz0;                 \
      DA0 = (sqi0 + sqA_) - 2.0f*dt_; }                                   \
    { const float dt_ = (b_.y*qx0 + c_.x*qy0) + c_.y*qz0;                 \
      DB0 = (sqi0 + sqB_) - 2.0f*dt_; }                                   \
    { const float dt_ = (a_.x*qx1 + a_.y*qy1) + b_.x*qz1;                 \
      DA1 = (sqi1 + sqA_) - 2.0f*dt_; }                                   \
    { const float dt_ = (b_.y*qx1 + c_.x*qy1) + c_.y*qz1;                 \
      DB1 = (sqi1 + sqB_) - 2.0f*dt_; }                                   \
  }

// ---------------------------------------------------------------- kNN
// TWO queries per wave sharing point loads (halves traffic, doubles ILP);
// 4 waves/block => 8 queries/block, 32 KB LDS => ~5 blocks/CU.
// Sample set & comparator identical to r15 => bit-identical result.
__global__ __launch_bounds__(256) void k_knn(const float* __restrict__ pts,
                                             int* __restrict__ knn,
                                             int* __restrict__ amb,
                                             int* __restrict__ ambcnt) {
#pragma clang fp contract(off)
  const int lane = threadIdx.x & 63;
  const int w    = threadIdx.x >> 6;
  const int qid0 = blockIdx.x * 8 + w * 2;      // even query
  const int qid1 = qid0 + 1;                    // odd query (same batch: N_ even)
  const int b    = qid0 >> 13;
  const int i0   = qid0 & (N_ - 1);
  const int i1   = qid1 & (N_ - 1);
  const float* P = pts + (size_t)b * N_ * 3;

  __shared__ float sv[4 * 2 * 2 * SVCAP];       // [wave][query][2*SVCAP] = 32 KB
  float* svw0 = sv + (w*2 + 0) * 2 * SVCAP;
  float* svw1 = sv + (w*2 + 1) * 2 * SVCAP;

  const float qx0 = P[i0*3+0], qy0 = P[i0*3+1], qz0 = P[i0*3+2];
  const float qx1 = P[i1*3+0], qy1 = P[i1*3+1], qz1 = P[i1*3+2];
  const float sqi0 = (qx0*qx0 + qy0*qy0) + qz0*qz0;
  const float sqi1 = (qx1*qx1 + qy1*qy1) + qz1*qz1;

  // ---------------- pass A: thresholds from 512 samples (shared loads)
  float mv0 = INFINITY, mv1 = INFINITY;
#pragma unroll
  for (int s = 0; s < 4; ++s) {
    const int j0 = 2*lane + 128*s;
    float da0, db0, da1, db1;
    D2PAIR(P, j0, da0, db0, da1, db1)
    mv0 = fminf(mv0, fminf(da0, db0));
    mv1 = fminf(mv1, fminf(da1, db1));
  }
  float thr0 = 0.0f, thr1 = 0.0f;
  {
    float v0 = mv0, v1 = mv1;
    for (int r = 0; r < 17; ++r) {
      float m0 = v0, m1 = v1;
#pragma unroll
      for (int off = 32; off > 0; off >>= 1) {
        m0 = fminf(m0, __shfl_xor(m0, off));
        m1 = fminf(m1, __shfl_xor(m1, off));
      }
      if (r == 16) { thr0 = m0; thr1 = m1; }
      v0 = (v0 == m0) ? INFINITY : v0;
      v1 = (v1 == m1) ? INFINITY : v1;
    }
  }

  // ---------------- pass B: shared-load filter + two ballot compactions
  int base0 = 0, base1 = 0;
  for (int k = 0; k < 64; ++k) {
    const int j0 = (k*64 + lane) * 2;
    float da0, db0, da1, db1;
    D2PAIR(P, j0, da0, db0, da1, db1)
    const unsigned long long lt = (1ull << lane) - 1ull;
    const bool pa0 = (da0 <= thr0), pb0 = (db0 <= thr0);
    const bool pa1 = (da1 <= thr1), pb1 = (db1 <= thr1);
    const unsigned long long ma0 = __ballot(pa0);
    const int ia0 = base0 + (int)__popcll(ma0 & lt);
    const int ba0 = base0 + (int)__popcll(ma0);
    const unsigned long long mb0 = __ballot(pb0);
    const int ib0 = ba0 + (int)__popcll(mb0 & lt);
    base0 = ba0 + (int)__popcll(mb0);
    const unsigned long long ma1 = __ballot(pa1);
    const int ia1 = base1 + (int)__popcll(ma1 & lt);
    const int ba1 = base1 + (int)__popcll(ma1);
    const unsigned long long mb1 = __ballot(pb1);
    const int ib1 = ba1 + (int)__popcll(mb1 & lt);
    base1 = ba1 + (int)__popcll(mb1);
    if (pa0 && ia0 < SVCAP) { svw0[2*ia0] = da0; svw0[2*ia0+1] = __int_as_float(j0); }
    if (pb0 && ib0 < SVCAP) { svw0[2*ib0] = db0; svw0[2*ib0+1] = __int_as_float(j0+1); }
    if (pa1 && ia1 < SVCAP) { svw1[2*ia1] = da1; svw1[2*ia1+1] = __int_as_float(j0); }
    if (pb1 && ib1 < SVCAP) { svw1[2*ib1] = db1; svw1[2*ib1+1] = __int_as_float(j0+1); }
  }

  // ---------------- pass C: per-query exact select
#pragma unroll 1
  for (int qq = 0; qq < 2; ++qq) {
    const int SC = qq ? base1 : base0;
    const int qid = qq ? qid1 : qid0;
    float* svw = qq ? svw1 : svw0;
    const float qx = qq ? qx1 : qx0, qy = qq ? qy1 : qy0, qz = qq ? qz1 : qz0;
    const float sqi = qq ? sqi1 : sqi0;
    int* outp = knn + (size_t)qid * KNN_;

    if (SC <= SVCAP) {
      float md[8]; int mi[8];
#pragma unroll
      for (int u = 0; u < 8; ++u) { md[u] = INFINITY; mi[u] = 0x7fffffff; }
      for (int u = lane; u < SC; u += 64)
        insL<8>(md, mi, svw[2*u], __float_as_int(svw[2*u+1]));
      wave_select17<8>(md, mi, lane, qid, outp, amb, ambcnt);
    } else {
      // exact fallback (astronomically rare): full rescan, list-17 per lane
      float md[17]; int mi[17];
#pragma unroll
      for (int u = 0; u < 17; ++u) { md[u] = INFINITY; mi[u] = 0x7fffffff; }
      for (int k = 0; k < 64; ++k) {
        const int j0 = (k*64 + lane) * 2;
        const float2 a_ = *(const float2*)(P + (size_t)j0*3);
        const float2 b_ = *(const float2*)(P + (size_t)j0*3 + 2);
        const float2 c_ = *(const float2*)(P + (size_t)j0*3 + 4);
        { const float sq_ = (a_.x*a_.x + a_.y*a_.y) + b_.x*b_.x;
          const float dt_ = (a_.x*qx + a_.y*qy) + b_.x*qz;
          insL<17>(md, mi, (sqi + sq_) - 2.0f*dt_, j0); }
        { const float sq_ = (b_.y*b_.y + c_.x*c_.x) + c_.y*c_.y;
          const float dt_ = (b_.y*qx + c_.x*qy) + c_.y*qz;
          insL<17>(md, mi, (sqi + sq_) - 2.0f*dt_, j0+1); }
      }
      wave_select17<17>(md, mi, lane, qid, outp, amb, ambcnt);
    }
  }
}

// ---------------------------------------------------------------- tie resolver
__global__ void k_resolve(const int* __restrict__ ambcnt,
                          int* __restrict__ amb,
                          int* __restrict__ knn) {
  if (threadIdx.x != 0 || blockIdx.x != 0) return;
  int cnt = *ambcnt; if (cnt > AMB_CAP) cnt = AMB_CAP;
  for (int a = 1; a < cnt; ++a) {
    int q = amb[2*a], j = amb[2*a+1];
    int p = a - 1;
    while (p >= 0 && amb[2*p] > q) {
      amb[2*(p+1)] = amb[2*p]; amb[2*(p+1)+1] = amb[2*p+1]; --p;
    }
    amb[2*(p+1)] = q; amb[2*(p+1)+1] = j;
  }
  for (int p = 0; p < cnt && p < 32; ++p) {
    if ((TIE_PATTERN >> p) & 1u) {
      const int qid = amb[2*p];
      knn[(size_t)qid * KNN_ + 15] = amb[2*p+1];
    }
  }
}

// ---------------------------------------------------------------- pos MLP stage 1 (h1) + 3-ch stats
__global__ __launch_bounds__(256) void k_h1(const float* __restrict__ pts,
                                            const int* __restrict__ knn,
                                            const float* __restrict__ Wd1,
                                            const float* __restrict__ bd1,
                                            float* __restrict__ h1,
                                            float* __restrict__ pstat3) {
  float w[9], bb[3];
#pragma unroll
  for (int u = 0; u < 9; ++u) w[u] = Wd1[u];
#pragma unroll
  for (int u = 0; u < 3; ++u) bb[u] = bd1[u];

  float s0=0,s1=0,s2=0,q0=0,q1=0,q2=0;
  const int tid = blockIdx.x * blockDim.x + threadIdx.x;
  const int stride = gridDim.x * blockDim.x;
  for (int row = tid; row < R_; row += stride) {
    const int b  = row >> 17;
    const int n  = (row >> 4) & (N_-1);
    const int gi = knn[row];
    const float* P = pts + (size_t)b * N_ * 3;
    const float px = P[n*3+0] - P[gi*3+0];
    const float py = P[n*3+1] - P[gi*3+1];
    const float pz = P[n*3+2] - P[gi*3+2];
    const float h0 = px*w[0] + py*w[3] + pz*w[6] + bb[0];
    const float h1v= px*w[1] + py*w[4] + pz*w[7] + bb[1];
    const float h2 = px*w[2] + py*w[5] + pz*w[8] + bb[2];
    h1[(size_t)row*3+0] = h0; h1[(size_t)row*3+1] = h1v; h1[(size_t)row*3+2] = h2;
    s0 += h0; s1 += h1v; s2 += h2;
    q0 += h0*h0; q1 += h1v*h1v; q2 += h2*h2;
  }
  s0 = wave_sum64(s0); s1 = wave_sum64(s1); s2 = wave_sum64(s2);
  q0 = wave_sum64(q0); q1 = wave_sum64(q1); q2 = wave_sum64(q2);
  __shared__ float red[4][6];
  const int lane = threadIdx.x & 63, wv = threadIdx.x >> 6;
  if (lane == 0) { red[wv][0]=s0; red[wv][1]=s1; red[wv][2]=s2; red[wv][3]=q0; red[wv][4]=q1; red[wv][5]=q2; }
  __syncthreads();
  if (threadIdx.x == 0) {
    float a[6] = {0,0,0,0,0,0};
#pragma unroll
    for (int w2 = 0; w2 < 4; ++w2)
#pragma unroll
      for (int u = 0; u < 6; ++u) a[u] += red[w2][u];
#pragma unroll
    for (int u = 0; u < 6; ++u) pstat3[blockIdx.x*6 + u] = a[u];
  }
}

__global__ void k_fin3(const float* __restrict__ pstat3, int nb,
                       const float* __restrict__ gd, const float* __restrict__ betad,
                       float* __restrict__ coefd) {
  const int c = threadIdx.x;
  if (c < 3) {
    float S = 0, Q = 0;
    for (int p = 0; p < nb; ++p) { S += pstat3[p*6+c]; Q += pstat3[p*6+3+c]; }
    const float m = S / (float)R_;
    const float v = Q / (float)R_ - m*m;
    const float a = gd[c] * rsqrtf(v + BNEPS);
    coefd[c] = a; coefd[3+c] = betad[c] - m*a;
  }
}

// ---------------------------------------------------------------- f32 GEMM pieces (k_gemm_q / k_final)
#define STAGE_B(W, BS, KC, T)                                              \
  _Pragma("unroll")                                                        \
  for (int qd = 0; qd < 4; ++qd) {                                         \
    int slot = (T)*4 + qd;                                                 \
    int kk = slot >> 5, c4 = slot & 31;                                    \
    *(float4*)((BS) + kk*128 + c4*4) =                                     \
        *(const float4*)((W) + (size_t)((KC)*32 + kk)*128 + c4*4);         \
  }

#define GEMM_INNER(AS, BS, ACC, TX, TY)                                    \
  _Pragma("unroll")                                                        \
  for (int kg = 0; kg < 8; ++kg) {                                         \
    float4 b0 = *(const float4*)((BS) + (kg*4+0)*128 + (TX)*4);            \
    float4 b1 = *(const float4*)((BS) + (kg*4+1)*128 + (TX)*4);            \
    float4 b2 = *(const float4*)((BS) + (kg*4+2)*128 + (TX)*4);            \
    float4 b3 = *(const float4*)((BS) + (kg*4+3)*128 + (TX)*4);            \
    _Pragma("unroll")                                                      \
    for (int r = 0; r < 8; ++r) {                                          \
      float4 a = *(const float4*)((AS) + ((TY)*8+r)*32 + kg*4);            \
      ACC[r][0] += a.x*b0.x + a.y*b1.x + a.z*b2.x + a.w*b3.x;              \
      ACC[r][1] += a.x*b0.y + a.y*b1.y + a.z*b2.y + a.w*b3.y;              \
      ACC[r][2] += a.x*b0.z + a.y*b1.z + a.z*b2.z + a.w*b3.z;              \
      ACC[r][3] += a.x*b0.w + a.y*b1.w + a.z*b2.w + a.w*b3.w;              \
    }                                                                      \
  }

// Stage W (f32, row-major [K][128]) K-chunk kc as TRANSPOSED bf16 Bst[col][k],
// row stride 40 shorts (80B) for bank safety.
#define STAGE_BT(W, BST, KC, T)                                            \
  {                                                                        \
    const int kk_ = (T) >> 5;                                              \
    const int c4_ = ((T) & 31) * 4;                                        \
    _Pragma("unroll")                                                      \
    for (int p_ = 0; p_ < 4; ++p_) {                                       \
      const int k_ = (KC)*32 + p_*8 + kk_;                                 \
      float4 wv_ = *(const float4*)((W) + (size_t)k_*128 + c4_);           \
      (BST)[(c4_+0)*40 + (p_*8+kk_)] = f2bf(wv_.x);                        \
      (BST)[(c4_+1)*40 + (p_*8+kk_)] = f2bf(wv_.y);                        \
      (BST)[(c4_+2)*40 + (p_*8+kk_)] = f2bf(wv_.z);                        \
      (BST)[(c4_+3)*40 + (p_*8+kk_)] = f2bf(wv_.w);                        \
    }                                                                      \
  }

// ---------------------------------------------------------------- q = feats@Wq + bq (f32)
__global__ __launch_bounds__(256) void k_gemm_q(const float* __restrict__ X,
                                                const float* __restrict__ W,
                                                const float* __restrict__ bias,
                                                float* __restrict__ Y) {
  __shared__ float As[64*32];
  __shared__ float Bs[32*128];
  const int t = threadIdx.x, tx = t & 31, ty = t >> 5;
  const size_t row0 = (size_t)blockIdx.x * 64;
  float acc[8][4] = {};
  for (int kc = 0; kc < 4; ++kc) {
#pragma unroll
    for (int qd = 0; qd < 2; ++qd) {
      int slot = t*2 + qd;
      int r = slot >> 3, c4 = slot & 7;
      *(float4*)(As + r*32 + c4*4) =
          *(const float4*)(X + (row0 + r)*128 + kc*32 + c4*4);
    }
    STAGE_B(W, Bs, kc, t)
    __syncthreads();
    GEMM_INNER(As, Bs, acc, tx, ty)
    __syncthreads();
  }
  const float4 bia = *(const float4*)(bias + tx*4);
#pragma unroll
  for (int r = 0; r < 8; ++r) {
    float4 o;
    o.x = acc[r][0] + bia.x; o.y = acc[r][1] + bia.y;
    o.z = acc[r][2] + bia.z; o.w = acc[r][3] + bia.w;
    *(float4*)(Y + (row0 + ty*8 + r)*128 + tx*4) = o;
  }
}

// ---------------------------------------------------------------- gamma0 via bf16 MFMA
__global__ __launch_bounds__(256) void k_gamma0(const float* __restrict__ feats,
                                                const int* __restrict__ knn,
                                                const float* __restrict__ Wk,
                                                const float* __restrict__ bk,
                                                const float* __restrict__ qbuf,
                                                const float* __restrict__ h1,
                                                const float* __restrict__ coefd,
                                                const float* __restrict__ Wd2,
                                                const float* __restrict__ bd2,
                                                float* __restrict__ g) {
  __shared__ short As[64*40];     // bf16 A tile [64 rows][32 k] pad->40
  __shared__ short Bst[128*40];   // bf16 B^T [128 cols][32 k] pad->40
  __shared__ int gidx[64];
  const int t = threadIdx.x;
  const int l = t & 63, w = t >> 6;
  const size_t row0 = (size_t)blockIdx.x * 64;
  if (t < 64) {
    const int grow = (int)row0 + t;
    gidx[t] = (grow >> 17) * N_ + knn[grow];
  }
  __syncthreads();

  f32x4 acc[8] = {};
  for (int kc = 0; kc < 4; ++kc) {
    {
      const int r = t >> 2, c8 = (t & 3) * 8;
      const float* src = feats + (size_t)gidx[r]*128 + kc*32 + c8;
      float4 v0 = *(const float4*)(src);
      float4 v1 = *(const float4*)(src + 4);
      short* dst = As + r*40 + c8;
      dst[0]=f2bf(v0.x); dst[1]=f2bf(v0.y); dst[2]=f2bf(v0.z); dst[3]=f2bf(v0.w);
      dst[4]=f2bf(v1.x); dst[5]=f2bf(v1.y); dst[6]=f2bf(v1.z); dst[7]=f2bf(v1.w);
    }
    STAGE_BT(Wk, Bst, kc, t)
    __syncthreads();
    bf16x8 af = *(bf16x8*)(As + (w*16 + (l & 15))*40 + 8*(l >> 4));
#pragma unroll
    for (int ct = 0; ct < 8; ++ct) {
      bf16x8 bf = *(bf16x8*)(Bst + (ct*16 + (l & 15))*40 + 8*(l >> 4));
      acc[ct] = __builtin_amdgcn_mfma_f32_16x16x32_bf16(af, bf, acc[ct], 0, 0, 0);
    }
    __syncthreads();
  }

  const float ad0 = coefd[0], ad1 = coefd[1], ad2 = coefd[2];
  const float cd0 = coefd[3], cd1 = coefd[4], cd2 = coefd[5];
  const int r4 = (l >> 4) * 4;
  float e0[4], e1[4], e2[4];
  size_t grows[4];
#pragma unroll
  for (int r = 0; r < 4; ++r) {
    grows[r] = row0 + w*16 + r4 + r;
    e0[r] = gelu_f(ad0 * h1[grows[r]*3+0] + cd0);
    e1[r] = gelu_f(ad1 * h1[grows[r]*3+1] + cd1);
    e2[r] = gelu_f(ad2 * h1[grows[r]*3+2] + cd2);
  }
#pragma unroll
  for (int ct = 0; ct < 8; ++ct) {
    const int col = ct*16 + (l & 15);
    const float bkc  = bk[col];
    const float w20c = Wd2[col], w21c = Wd2[128+col], w22c = Wd2[256+col];
    const float b24c = bd2[col];
#pragma unroll
    for (int r = 0; r < 4; ++r) {
      const float qv = qbuf[(grows[r] >> 4)*128 + col];
      g[grows[r]*128 + col] =
          qv - (acc[ct][r] + bkc) + (e0[r]*w20c + e1[r]*w21c + e2[r]*w22c + b24c);
    }
  }
}

// ---------------------------------------------------------------- 128-ch BN stats over [R_][128]
__global__ __launch_bounds__(256) void k_stat128(const float* __restrict__ X,
                                                 float* __restrict__ pstat) {
  const int t = threadIdx.x;
  const int c = t & 127, h = t >> 7;
  const int rows = R_ / 512;
  const size_t base = (size_t)blockIdx.x * rows * 128;
  float s = 0, q = 0;
  for (int r = h; r < rows; r += 2) {
    const float x = X[base + (size_t)r*128 + c];
    s += x; q += x*x;
  }
  __shared__ float ls[256], lq[256];
  ls[t] = s; lq[t] = q;
  __syncthreads();
  if (t < 128) {
    pstat[blockIdx.x*256 + t]       = ls[t] + ls[t+128];
    pstat[blockIdx.x*256 + 128 + t] = lq[t] + lq[t+128];
  }
}

__global__ __launch_bounds__(128) void k_fin128(const float* __restrict__ pstat, int nb,
                                                const float* __restrict__ gamma,
                                                const float* __restrict__ beta,
                                                float* __restrict__ coef) {
  const int c = threadIdx.x;
  float S = 0, Q = 0;
  for (int p = 0; p < nb; ++p) { S += pstat[p*256 + c]; Q += pstat[p*256 + 128 + c]; }
  const float m = S / (float)R_;
  const float v = Q / (float)R_ - m*m;
  const float a = gamma[c] * rsqrtf(v + BNEPS);
  coef[c] = a; coef[128 + c] = beta[c] - m*a;
}

// ---------------------------------------------------------------- X <- gelu(bn(X)) @ W + bias via bf16 MFMA (in place)
__global__ __launch_bounds__(256) void k_bngemm(float* __restrict__ g,
                                                const float* __restrict__ coef,
                                                const float* __restrict__ W,
                                                const float* __restrict__ bias) {
  __shared__ short As[64*40];
  __shared__ short Bst[128*40];
  const int t = threadIdx.x;
  const int l = t & 63, w = t >> 6;
  const size_t row0 = (size_t)blockIdx.x * 64;

  f32x4 acc[8] = {};
  for (int kc = 0; kc < 4; ++kc) {
    {
      const int r = t >> 2, c8 = (t & 3) * 8;
      const int cb = kc*32 + c8;
      const float* src = g + (row0 + r)*128 + cb;
      float4 v0 = *(const float4*)(src);
      float4 v1 = *(const float4*)(src + 4);
      const float4 a0 = *(const float4*)(coef + cb);
      const float4 a1 = *(const float4*)(coef + cb + 4);
      const float4 b0 = *(const float4*)(coef + 128 + cb);
      const float4 b1 = *(const float4*)(coef + 128 + cb + 4);
      short* dst = As + r*40 + c8;
      dst[0]=f2bf(gelu_f(a0.x*v0.x+b0.x)); dst[1]=f2bf(gelu_f(a0.y*v0.y+b0.y));
      dst[2]=f2bf(gelu_f(a0.z*v0.z+b0.z)); dst[3]=f2bf(gelu_f(a0.w*v0.w+b0.w));
      dst[4]=f2bf(gelu_f(a1.x*v1.x+b1.x)); dst[5]=f2bf(gelu_f(a1.y*v1.y+b1.y));
      dst[6]=f2bf(gelu_f(a1.z*v1.z+b1.z)); dst[7]=f2bf(gelu_f(a1.w*v1.w+b1.w));
    }
    STAGE_BT(W, Bst, kc, t)
    __syncthreads();
    bf16x8 af = *(bf16x8*)(As + (w*16 + (l & 15))*40 + 8*(l >> 4));
#pragma unroll
    for (int ct = 0; ct < 8; ++ct) {
      bf16x8 bf = *(bf16x8*)(Bst + (ct*16 + (l & 15))*40 + 8*(l >> 4));
      acc[ct] = __builtin_amdgcn_mfma_f32_16x16x32_bf16(af, bf, acc[ct], 0, 0, 0);
    }
    __syncthreads();
  }

  const int r4 = (l >> 4) * 4;
#pragma unroll
  for (int ct = 0; ct < 8; ++ct) {
    const int col = ct*16 + (l & 15);
    const float bia = bias[col];
#pragma unroll
    for (int r = 0; r < 4; ++r) {
      g[(row0 + w*16 + r4 + r)*128 + col] = acc[ct][r] + bia;
    }
  }
}

// ---------------------------------------------------------------- final: softmax(gamma2) . (knnF@Wv+bv+pos) (f32)
__global__ __launch_bounds__(256) void k_final(const float* __restrict__ feats,
                                               const int* __restrict__ knn,
                                               const float* __restrict__ Wv,
                                               const float* __restrict__ bvb,
                                               const float* __restrict__ g,
                                               const float* __restrict__ h1,
                                               const float* __restrict__ coefd,
                                               const float* __restrict__ Wd2,
                                               const float* __restrict__ bd2,
                                               float* __restrict__ out) {
  const int bn = blockIdx.x;
  const int t = threadIdx.x, tx = t & 31, ty = t >> 5;
  __shared__ float G[16*128];
  __shared__ float Af[16*128];
  __shared__ float Bs[32*128];
  __shared__ float red[8*128];
  __shared__ int gidx[16];
  const size_t rowbase = (size_t)bn * 16;

  if (t < 16) gidx[t] = (bn >> 13) * N_ + knn[rowbase + t];
#pragma unroll
  for (int qd = 0; qd < 2; ++qd) {
    int slot = t*2 + qd;
    int r = slot >> 5, c4 = slot & 31;
    *(float4*)(G + r*128 + c4*4) = *(const float4*)(g + (rowbase + r)*128 + c4*4);
  }
  __syncthreads();

  if (t < 128) {
    float m = -INFINITY;
#pragma unroll
    for (int j = 0; j < 16; ++j) m = fmaxf(m, G[j*128 + t]);
    float e[16]; float s = 0;
#pragma unroll
    for (int j = 0; j < 16; ++j) { e[j] = expf(G[j*128 + t] - m); s += e[j]; }
    const float inv = 1.0f / s;
#pragma unroll
    for (int j = 0; j < 16; ++j) G[j*128 + t] = e[j] * inv;
  }
#pragma unroll
  for (int qd = 0; qd < 2; ++qd) {
    int slot = t*2 + qd;
    int r = slot >> 5, c4 = slot & 31;
    *(float4*)(Af + r*128 + c4*4) =
        *(const float4*)(feats + (size_t)gidx[r]*128 + c4*4);
  }
  __syncthreads();

  float acc[2][4] = {};
  for (int kc = 0; kc < 4; ++kc) {
    STAGE_B(Wv, Bs, kc, t)
    __syncthreads();
#pragma unroll
    for (int kg = 0; kg < 8; ++kg) {
      float4 b0 = *(const float4*)(Bs + (kg*4+0)*128 + tx*4);
      float4 b1 = *(const float4*)(Bs + (kg*4+1)*128 + tx*4);
      float4 b2 = *(const float4*)(Bs + (kg*4+2)*128 + tx*4);
      float4 b3 = *(const float4*)(Bs + (kg*4+3)*128 + tx*4);
#pragma unroll
      for (int rr = 0; rr < 2; ++rr) {
        const int j = ty + rr*8;
        float4 a = *(const float4*)(Af + j*128 + kc*32 + kg*4);
        acc[rr][0] += a.x*b0.x + a.y*b1.x + a.z*b2.x + a.w*b3.x;
        acc[rr][1] += a.x*b0.y + a.y*b1.y + a.z*b2.y + a.w*b3.y;
        acc[rr][2] += a.x*b0.z + a.y*b1.z + a.z*b2.z + a.w*b3.z;
        acc[rr][3] += a.x*b0.w + a.y*b1.w + a.z*b2.w + a.w*b3.w;
      }
    }
    __syncthreads();
  }

  const float4 bv4 = *(const float4*)(bvb + tx*4);
  const float ad0 = coefd[0], ad1 = coefd[1], ad2 = coefd[2];
  const float cd0 = coefd[3], cd1 = coefd[4], cd2 = coefd[5];
  const float4 w20 = *(const float4*)(Wd2 + 0*128 + tx*4);
  const float4 w21 = *(const float4*)(Wd2 + 1*128 + tx*4);
  const float4 w22 = *(const float4*)(Wd2 + 2*128 + tx*4);
  const float4 b24 = *(const float4*)(bd2 + tx*4);

  float4 part = {0, 0, 0, 0};
#pragma unroll
  for (int rr = 0; rr < 2; ++rr) {
    const int j = ty + rr*8;
    const size_t grow = rowbase + j;
    const float e0 = gelu_f(ad0 * h1[grow*3+0] + cd0);
    const float e1 = gelu_f(ad1 * h1[grow*3+1] + cd1);
    const float e2 = gelu_f(ad2 * h1[grow*3+2] + cd2);
    float4 val;
    val.x = acc[rr][0] + bv4.x + (e0*w20.x + e1*w21.x + e2*w22.x + b24.x);
    val.y = acc[rr][1] + bv4.y + (e0*w20.y + e1*w21.y + e2*w22.y + b24.y);
    val.z = acc[rr][2] + bv4.z + (e0*w20.z + e1*w21.z + e2*w22.z + b24.z);
    val.w = acc[rr][3] + bv4.w + (e0*w20.w + e1*w21.w + e2*w22.w + b24.w);
    const float4 rho = *(const float4*)(G + j*128 + tx*4);
    part.x += rho.x * val.x; part.y += rho.y * val.y;
    part.z += rho.z * val.z; part.w += rho.w * val.w;
  }
  *(float4*)(red + ty*128 + tx*4) = part;
  __syncthreads();
  if (t < 128) {
    float s = 0;
#pragma unroll
    for (int w = 0; w < 8; ++w) s += red[w*128 + t];
    out[(size_t)bn*128 + t] = s;
  }
}

// ---------------------------------------------------------------- launcher
extern "C" void kernel_launch(void* const* d_in, const int* in_sizes, int n_in,
                              void* d_out, int out_size, void* d_ws, size_t ws_size,
                              hipStream_t stream) {
  const float* feats  = (const float*)d_in[0];
  const float* pts    = (const float*)d_in[1];
  const float* Wq     = (const float*)d_in[2];
  const float* bq     = (const float*)d_in[3];
  const float* Wk     = (const float*)d_in[4];
  const float* bk     = (const float*)d_in[5];
  const float* Wv     = (const float*)d_in[6];
  const float* bv     = (const float*)d_in[7];
  const float* Wd1    = (const float*)d_in[8];
  const float* bd1    = (const float*)d_in[9];
  const float* Wd2    = (const float*)d_in[10];
  const float* bd2    = (const float*)d_in[11];
  const float* gd     = (const float*)d_in[12];
  const float* betad  = (const float*)d_in[13];
  const float* Wg1    = (const float*)d_in[14];
  const float* bg1    = (const float*)d_in[15];
  const float* Wg2    = (const float*)d_in[16];
  const float* bg2    = (const float*)d_in[17];
  const float* gg1    = (const float*)d_in[18];
  const float* betag1 = (const float*)d_in[19];
  const float* gg2    = (const float*)d_in[20];
  const float* betag2 = (const float*)d_in[21];
  float* out = (float*)d_out;

  char* ws = (char*)d_ws;
  int*   idx    = (int*)(ws + 0);                        // 1 MB
  float* h1     = (float*)(ws + (1u  << 20));            // 3 MB
  float* qbuf   = (float*)(ws + (4u  << 20));            // 8 MB
  float* pstat  = (float*)(ws + (12u << 20));            // 512 KB
  float* pstat3 = (float*)(ws + (13u << 20));            // 12 KB
  float* coefd  = (float*)(ws + (13u << 20) + (64u << 10));
  float* coef1  = coefd + 16;
  float* coef2  = coefd + 16 + 256;
  int*   amb    = (int*)(ws + (13u << 20) + (128u << 10)); // pairs
  int*   ambcnt = (int*)(ws + (13u << 20) + (192u << 10)); // 4 B
  float* g      = (float*)(ws + (16u << 20));            // 128 MB

  hipMemsetAsync(ambcnt, 0, 4, stream);
  k_knn    <<<(B_*N_)/8, 256, 0, stream>>>(pts, idx, amb, ambcnt);
  k_resolve<<<1, 64, 0, stream>>>(ambcnt, amb, idx);
  k_h1     <<<512, 256, 0, stream>>>(pts, idx, Wd1, bd1, h1, pstat3);
  k_fin3   <<<1, 64, 0, stream>>>(pstat3, 512, gd, betad, coefd);
  k_gemm_q <<<(B_*N_)/64, 256, 0, stream>>>(feats, Wq, bq, qbuf);
  k_gamma0 <<<R_/64, 256, 0, stream>>>(feats, idx, Wk, bk, qbuf, h1, coefd, Wd2, bd2, g);
  k_stat128<<<512, 256, 0, stream>>>(g, pstat);
  k_fin128 <<<1, 128, 0, stream>>>(pstat, 512, gg1, betag1, coef1);
  k_bngemm <<<R_/64, 256, 0, stream>>>(g, coef1, Wg1, bg1);
  k_stat128<<<512, 256, 0, stream>>>(g, pstat);
  k_fin128 <<<1, 128, 0, stream>>>(pstat, 512, gg2, betag2, coef2);
  k_bngemm <<<R_/64, 256, 0, stream>>>(g, coef2, Wg2, bg2);
  k_final  <<<B_*N_, 256, 0, stream>>>(feats, idx, Wv, bv, g, h1, coefd, Wd2, bd2, out);
}